// Round 5
// baseline (431.318 us; speedup 1.0000x reference)
//
#include <hip/hip_runtime.h>

// AttnBlock B=32, C=512, N=1024. All GEMMs via bf16 MFMA 16x16x32.
// 256x256 tile, BK=64, 8 waves (2M x 4N), 128KB LDS double-buffer,
// 8-phase schedule, counted vmcnt, setprio, XCD-chunked swizzle,
// NT-tile persistence. Softmax fused: MODE2 emits row partials,
// comb_kernel folds them, MODE3 applies exp((s-M))*inv on A-staging.
// Layouts: h[b][n][c], q[b][n][c], k[b][n][c], v[b][c][n], O[b][n][c].
// GEMM: C[m][n] = sum_k A[m][k]*B[n][k]  (A: MxK rm, B: NxK rm, K-contig)

#define C_DIM 512
#define N_PIX 1024
#define BATCH 32
#define CPG 16
#define EPS 1e-6f
#define SCALE 0.044194173824159216f  // 512^-0.5
#define ESTRIDE 66                   // f32 epilogue LDS row stride (floats)
#define ESTRU   72                   // bf16 epilogue LDS row stride (u16)

typedef unsigned short u16;
typedef __attribute__((ext_vector_type(8))) short bf16x8;
typedef __attribute__((ext_vector_type(4))) float f32x4;
typedef __attribute__((ext_vector_type(2))) float f32x2;

static __device__ __forceinline__ float bf2f(u16 u) {
    union { unsigned int i; float f; } v; v.i = ((unsigned int)u) << 16; return v.f;
}
static __device__ __forceinline__ u16 f2bf(float f) {
    union { float f; unsigned int i; } v; v.f = f;
    unsigned int r = v.i + 0x7fffu + ((v.i >> 16) & 1u);
    return (u16)(r >> 16);
}

static __device__ __forceinline__ void gl_lds16(const u16* g, u16* l) {
    __builtin_amdgcn_global_load_lds(
        (const __attribute__((address_space(1))) unsigned int*)g,
        (__attribute__((address_space(3))) unsigned int*)l,
        16, 0, 0);
}

#define BAR()   __builtin_amdgcn_s_barrier()
#define SCHED() __builtin_amdgcn_sched_barrier(0x7)
#define LGKM0() asm volatile("s_waitcnt lgkmcnt(0)" ::: "memory")

// ------------------------------------------------- weights->bf16 + GN stats
__global__ __launch_bounds__(256) void prep_kernel(
        const float* __restrict__ wq, const float* __restrict__ wk,
        const float* __restrict__ wv, const float* __restrict__ wp,
        u16* __restrict__ out, const float* __restrict__ x,
        float* __restrict__ stats) {
    int blk = blockIdx.x;
    if (blk < 1024) {   // weight convert
        int i = blk * 256 + threadIdx.x;
        int mat = i >> 16;
        const float* src = (mat == 0) ? wq : (mat == 1) ? wk : (mat == 2) ? wv : wp;
        float4 v = ((const float4*)src)[i & 65535];
        ushort4 o;
        o.x = f2bf(v.x); o.y = f2bf(v.y); o.z = f2bf(v.z); o.w = f2bf(v.w);
        *(ushort4*)&out[(size_t)i * 4] = o;
        return;
    }
    blk -= 1024;        // group-norm stats for (b,g)
    int b = blk >> 5, g = blk & 31;
    const float4* xv = (const float4*)(x + ((size_t)(b * C_DIM + g * CPG)) * N_PIX);
    int tid = threadIdx.x;
    float s = 0.f, sq = 0.f;
#pragma unroll 4
    for (int i = tid; i < (CPG * N_PIX) / 4; i += 256) {
        float4 v = xv[i];
        s  += v.x + v.y + v.z + v.w;
        sq += v.x * v.x + v.y * v.y + v.z * v.z + v.w * v.w;
    }
#pragma unroll
    for (int m = 1; m < 64; m <<= 1) {
        s += __shfl_xor(s, m);
        sq += __shfl_xor(sq, m);
    }
    __shared__ float rs[4], rq[4];
    int wv_ = tid >> 6;
    if ((tid & 63) == 0) { rs[wv_] = s; rq[wv_] = sq; }
    __syncthreads();
    if (tid == 0) {
        float S = rs[0] + rs[1] + rs[2] + rs[3];
        float Q = rq[0] + rq[1] + rq[2] + rq[3];
        float mean = S * (1.0f / (CPG * N_PIX));
        float var  = Q * (1.0f / (CPG * N_PIX)) - mean * mean;
        stats[blk * 2] = mean;
        stats[blk * 2 + 1] = rsqrtf(var + EPS);
    }
}

// ------------------------------------------------- GN transform (coalesced)
__global__ __launch_bounds__(256) void gnt_kernel(
        const float* __restrict__ x, const float* __restrict__ gw,
        const float* __restrict__ gb, const float* __restrict__ stats,
        u16* __restrict__ h) {
    int blk = blockIdx.x;
    int b = blk >> 4, nc = blk & 15;
    int n0 = nc * 64;
    __shared__ u16 T[64 * 520];
    int tid = threadIdx.x;
    int cq = tid >> 4;
    int n4 = tid & 15;
    const float* xb = x + (size_t)b * C_DIM * N_PIX + n0;
#pragma unroll 4
    for (int pass = 0; pass < 32; ++pass) {
        int c = pass * 16 + cq;
        int g = c >> 4;
        float mean = stats[(b * 32 + g) * 2];
        float inv  = stats[(b * 32 + g) * 2 + 1];
        float sc = gw[c] * inv;
        float sh = gb[c] - mean * sc;
        float4 v = *(const float4*)(xb + (size_t)c * N_PIX + n4 * 4);
        int nn = n4 * 4;
        T[(nn + 0) * 520 + c] = f2bf(v.x * sc + sh);
        T[(nn + 1) * 520 + c] = f2bf(v.y * sc + sh);
        T[(nn + 2) * 520 + c] = f2bf(v.z * sc + sh);
        T[(nn + 3) * 520 + c] = f2bf(v.w * sc + sh);
    }
    __syncthreads();
    u16* hb = h + ((size_t)b * N_PIX + n0) * C_DIM;
    int rr = tid >> 5;
    int cc = (tid & 31) * 16;
#pragma unroll
    for (int p = 0; p < 8; ++p) {
        int n = p * 8 + rr;
        bf16x8 v0 = *(const bf16x8*)&T[n * 520 + cc];
        bf16x8 v1 = *(const bf16x8*)&T[n * 520 + cc + 8];
        *(bf16x8*)&hb[(size_t)n * C_DIM + cc] = v0;
        *(bf16x8*)&hb[(size_t)n * C_DIM + cc + 8] = v1;
    }
}

// ------------------------------------------------- softmax partial combine
// pstat[row][16] {m_p, s_p} -> sstat[row] {M, 1/sum}
__global__ __launch_bounds__(256) void comb_kernel(
        const float* __restrict__ pstat, float* __restrict__ sstat) {
    int row = blockIdx.x * 16 + (threadIdx.x >> 4);
    int p = threadIdx.x & 15;
    f32x2 mp = *(const f32x2*)&pstat[((size_t)row * 16 + p) * 2];
    float m = mp.x;
#pragma unroll
    for (int off = 1; off < 16; off <<= 1) m = fmaxf(m, __shfl_xor(m, off));
    float s = mp.y * __expf(mp.x - m);
#pragma unroll
    for (int off = 1; off < 16; off <<= 1) s += __shfl_xor(s, off);
    if (p == 0) {
        f32x2 o; o.x = m; o.y = 1.0f / s;
        *(f32x2*)&sstat[(size_t)row * 2] = o;
    }
}

// ------------------------------------------------------------- MFMA GEMM
// MODE 0: q&k (z=2b+mat), bf16 out +bias[col]
// MODE 1: v, bf16 out +bias[row]
// MODE 2: scores, bf16 out *SCALE, + row softmax partials -> pstat
// MODE 3: pv (A=S raw, exp((s-M))*inv applied on A-staging), bf16 out
// MODE 4: proj (B=O0/O1), f32 out +bias[row]+resid

#define MM(mq, nq) do { \
    _Pragma("unroll") \
    for (int t_ = 0; t_ < 4; ++t_) { \
        _Pragma("unroll") \
        for (int n_ = 0; n_ < 2; ++n_) { \
            _Pragma("unroll") \
            for (int ks_ = 0; ks_ < 2; ++ks_) \
                acc[(mq)*4 + t_][(nq)*2 + n_] = \
                    __builtin_amdgcn_mfma_f32_16x16x32_bf16( \
                        af[t_][ks_], bf[(nq)*2 + n_][ks_], \
                        acc[(mq)*4 + t_][(nq)*2 + n_], 0, 0, 0); \
        } \
    } \
} while (0)

template <int MODE, int NT>
__global__ __launch_bounds__(512, 2) void gemm_kernel(
        const u16* __restrict__ A, const u16* __restrict__ A2,
        const u16* __restrict__ B, const u16* __restrict__ B2,
        void* __restrict__ Cv, void* __restrict__ Cv2,
        const float* __restrict__ bias, const float* __restrict__ bias2,
        const float* __restrict__ xres,
        const float* __restrict__ sstat, float* __restrict__ pstat, int K,
        int rsA, int rsB, int rsC,
        long long bsA, long long bsB, long long bsC,
        int nx, int ny) {
    const int nwg = 256 * NT;

    const u16* tgA[NT]; const u16* tgB[NT];
    void* tout[NT]; const float* tbi[NT];
    const float* tst_[NT]; float* tps_[NT];
    int tcb[NT], tcolb[NT], trowb[NT], tpart_[NT];
#pragma unroll
    for (int tt = 0; tt < NT; ++tt) {
        int flat = blockIdx.x + tt * 256;
        int t = (flat & 7) * (nwg >> 3) + (flat >> 3);
        int bx = t % nx, by = (t / nx) % ny, bz = t / (nx * ny);
        int b = bz;
        const u16 *gA, *gB;
        void* out = Cv;
        const float* bi = bias;
        tst_[tt] = nullptr; tps_[tt] = nullptr; tpart_[tt] = 0;
        if (MODE == 0) {
            int mat = bz & 1; b = bz >> 1;
            gA = A + (size_t)b * bsA + (size_t)by * 256 * rsA;
            gB = B + (size_t)mat * 262144 + (size_t)bx * 256 * rsB;
            out = mat ? Cv2 : Cv;
            bi = mat ? bias2 : bias;
        } else if (MODE == 2) {
            gA = A + (size_t)b * bsA + (size_t)by * 256 * rsA;
            gB = B + (size_t)b * bsB + (size_t)bx * 256 * rsB;
            out = (b >= 16) ? Cv2 : Cv;
            tps_[tt] = pstat + (size_t)b * 1024 * 32;
            tpart_[tt] = bx * 4;
        } else if (MODE == 3) {
            gA = ((b >= 16) ? A2 : A) + (size_t)(b & 15) * bsA + (size_t)by * 256 * rsA;
            gB = B + (size_t)b * bsB + (size_t)bx * 256 * rsB;
            out = (b >= 16) ? Cv2 : Cv;
            tst_[tt] = sstat + ((size_t)b * 1024 + (size_t)by * 256) * 2;
        } else if (MODE == 4) {
            gA = A + (size_t)by * 256 * rsA;
            gB = ((b >= 16) ? B2 : B) + (size_t)(b & 15) * bsB + (size_t)bx * 256 * rsB;
        } else {  // MODE 1
            gA = A + (size_t)by * 256 * rsA;
            gB = B + (size_t)b * bsB + (size_t)bx * 256 * rsB;
        }
        tgA[tt] = gA; tgB[tt] = gB; tout[tt] = out; tbi[tt] = bi;
        tcb[tt] = (MODE == 2 || MODE == 3) ? (b & 15) : b;
        tcolb[tt] = bx * 256; trowb[tt] = by * 256;
    }

    // 128 KB: [0,16K)=A0 [16K,32K)=B0 [32K,48K)=A1 [48K,64K)=B1  (u16 idx)
    __shared__ __align__(16) u16 smem[65536];

    int tid = threadIdx.x;
    int lane = tid & 63, wave = tid >> 6;
    int wm = wave >> 2, wn = wave & 3;
    int quad = lane >> 4, l15 = lane & 15, l7 = lane & 7;
    int srow = tid >> 3;
    int lg = (tid & 7) ^ (srow & 7);

    const int nk = K >> 6;
    const int nit = nk >> 1;

    auto STG = [&](const u16* g, int rs, int buf, int isB, int hh, int kt) {
        const u16* src = g + (size_t)(hh * 128 + srow) * rs + (size_t)kt * 64 + lg * 8;
        u16* dst = &smem[buf * 32768 + isB * 16384 + (hh * 128 + srow) * 64 + (tid & 7) * 8];
        gl_lds16(src, dst);
        gl_lds16(src + (size_t)64 * rs, dst + 4096);
    };
    auto LDA = [&](int buf, int mq, int t_, int ks) -> bf16x8 {
        return *(const bf16x8*)&smem[buf * 32768 +
            (wm * 128 + mq * 64 + t_ * 16 + l15) * 64 + (((ks * 4 + quad) ^ l7) << 3)];
    };
    auto LDB = [&](int buf, int nt, int ks) -> bf16x8 {
        return *(const bf16x8*)&smem[buf * 32768 + 16384 +
            (wn * 64 + nt * 16 + l15) * 64 + (((ks * 4 + quad) ^ l7) << 3)];
    };

    // MODE3 reg-staged A with exp transform (issue early, write late)
    uint4 ar0, ar1, ar2, ar3;
    f32x2 sb0, sb1, sb2, sb3;
    auto AISS = [&](const u16* cA, int kt, const float* stb) {
        const u16* s0 = cA + (size_t)srow * rsA + (size_t)kt * 64 + lg * 8;
        ar0 = *(const uint4*)s0;
        ar1 = *(const uint4*)(s0 + (size_t)64 * rsA);
        ar2 = *(const uint4*)(s0 + (size_t)128 * rsA);
        ar3 = *(const uint4*)(s0 + (size_t)192 * rsA);
        sb0 = *(const f32x2*)&stb[(size_t)srow * 2];
        sb1 = *(const f32x2*)&stb[(size_t)(srow + 64) * 2];
        sb2 = *(const f32x2*)&stb[(size_t)(srow + 128) * 2];
        sb3 = *(const f32x2*)&stb[(size_t)(srow + 192) * 2];
    };
    auto XF = [&](uint4 r, f32x2 st) -> bf16x8 {
        bf16x8 o;
        const u16* e = (const u16*)&r;
#pragma unroll
        for (int i = 0; i < 8; ++i)
            o[i] = (short)f2bf(__expf(bf2f(e[i]) - st.x) * st.y);
        return o;
    };
    auto AWR = [&](int buf) {
        u16* d = &smem[buf * 32768 + srow * 64 + (tid & 7) * 8];
        *(bf16x8*)d = XF(ar0, sb0);
        *(bf16x8*)(d + 4096) = XF(ar1, sb1);
        *(bf16x8*)(d + 8192) = XF(ar2, sb2);
        *(bf16x8*)(d + 12288) = XF(ar3, sb3);
    };

    f32x4 acc[8][4];
    bf16x8 af[4][2], bf[4][2];

#pragma unroll
    for (int tt = 0; tt < NT; ++tt) {
        const bool hn = (tt + 1 < NT);
        const u16* cA = tgA[tt];
        const u16* cB = tgB[tt];
        const u16* nA = tgA[hn ? tt + 1 : tt];
        const u16* nB = tgB[hn ? tt + 1 : tt];
        const float* stb = tst_[tt];

        if (tt == 0) {
            if (MODE == 3) {
                STG(cB, rsB, 0, 1, 0, 0); STG(cB, rsB, 0, 1, 1, 0);
                AISS(cA, 0, stb);
                STG(cB, rsB, 1, 1, 0, 1); STG(cB, rsB, 1, 1, 1, 1);
                AWR(0);               // consumes AISS -> Bk0 (older) retired
                LGKM0();
            } else {
                STG(cB, rsB, 0, 1, 0, 0); STG(cB, rsB, 0, 1, 1, 0);
                STG(cA, rsA, 0, 0, 0, 0); STG(cA, rsA, 0, 0, 1, 0);
                STG(cB, rsB, 1, 1, 0, 1); STG(cB, rsB, 1, 1, 1, 1);
                asm volatile("s_waitcnt vmcnt(4)" ::: "memory");
            }
            SCHED(); BAR(); SCHED();
        }

#pragma unroll
        for (int mt = 0; mt < 8; ++mt)
#pragma unroll
            for (int nt = 0; nt < 4; ++nt)
                acc[mt][nt] = (f32x4){0.f, 0.f, 0.f, 0.f};

        for (int it = 0; it < nit; ++it) {
            const bool s = (it + 1 < nit);
            const int k1 = 2 * it + 1, k2 = 2 * it + 2, k3 = 2 * it + 3;

            // phase 1: read af(buf0,mq0)+bf(n0,1); stage A-buf1 (k1)
#pragma unroll
            for (int t_ = 0; t_ < 4; ++t_)
#pragma unroll
                for (int ks = 0; ks < 2; ++ks) af[t_][ks] = LDA(0, 0, t_, ks);
#pragma unroll
            for (int n = 0; n < 2; ++n)
#pragma unroll
                for (int ks = 0; ks < 2; ++ks) bf[n][ks] = LDB(0, n, ks);
            if (MODE == 3) AISS(cA, k1, stb);
            else STG(cA, rsA, 1, 0, 0, k1);
            SCHED(); BAR(); SCHED();
            __builtin_amdgcn_s_setprio(1); MM(0, 0); __builtin_amdgcn_s_setprio(0);
            SCHED(); BAR(); SCHED();

            // phase 2: read bf(n2,3) buf0; write A-buf1 (k1)
#pragma unroll
            for (int n = 2; n < 4; ++n)
#pragma unroll
                for (int ks = 0; ks < 2; ++ks) bf[n][ks] = LDB(0, n, ks);
            if (MODE == 3) AWR(1);
            else STG(cA, rsA, 1, 0, 1, k1);
            SCHED(); BAR(); SCHED();
            __builtin_amdgcn_s_setprio(1); MM(0, 1); __builtin_amdgcn_s_setprio(0);
            SCHED(); BAR(); SCHED();

            // phase 3: read af(buf0,mq1); stage B-buf0 (k2 | next k0) h0
#pragma unroll
            for (int t_ = 0; t_ < 4; ++t_)
#pragma unroll
                for (int ks = 0; ks < 2; ++ks) af[t_][ks] = LDA(0, 1, t_, ks);
            if (s) STG(cB, rsB, 0, 1, 0, k2);
            else if (hn) STG(nB, rsB, 0, 1, 0, 0);
            SCHED(); BAR(); SCHED();
            __builtin_amdgcn_s_setprio(1); MM(1, 1); __builtin_amdgcn_s_setprio(0);
            SCHED(); BAR(); SCHED();

            // phase 4: stage B-buf0 h1; MFMA; publish A-writes; counted vmcnt
            if (s) STG(cB, rsB, 0, 1, 1, k2);
            else if (hn) STG(nB, rsB, 0, 1, 1, 0);
            SCHED(); BAR(); SCHED();
            __builtin_amdgcn_s_setprio(1); MM(1, 0); __builtin_amdgcn_s_setprio(0);
            if (MODE == 3) LGKM0();
            if (s || hn) asm volatile("s_waitcnt vmcnt(4)" ::: "memory");
            else         asm volatile("s_waitcnt vmcnt(0)" ::: "memory");
            SCHED(); BAR(); SCHED();

            // phase 5: read af(buf1,mq0)+bf(n0,1); stage A-buf0 (k2|next k0)
#pragma unroll
            for (int t_ = 0; t_ < 4; ++t_)
#pragma unroll
                for (int ks = 0; ks < 2; ++ks) af[t_][ks] = LDA(1, 0, t_, ks);
#pragma unroll
            for (int n = 0; n < 2; ++n)
#pragma unroll
                for (int ks = 0; ks < 2; ++ks) bf[n][ks] = LDB(1, n, ks);
            if (s) { if (MODE == 3) AISS(cA, k2, stb); else STG(cA, rsA, 0, 0, 0, k2); }
            else if (hn) STG(nA, rsA, 0, 0, 0, 0);
            SCHED(); BAR(); SCHED();
            __builtin_amdgcn_s_setprio(1); MM(0, 0); __builtin_amdgcn_s_setprio(0);
            SCHED(); BAR(); SCHED();

            // phase 6: read bf(n2,3) buf1; write/stage A-buf0 h1
#pragma unroll
            for (int n = 2; n < 4; ++n)
#pragma unroll
                for (int ks = 0; ks < 2; ++ks) bf[n][ks] = LDB(1, n, ks);
            if (s) { if (MODE == 3) AWR(0); else STG(cA, rsA, 0, 0, 1, k2); }
            else if (hn) STG(nA, rsA, 0, 0, 1, 0);
            SCHED(); BAR(); SCHED();
            __builtin_amdgcn_s_setprio(1); MM(0, 1); __builtin_amdgcn_s_setprio(0);
            SCHED(); BAR(); SCHED();

            // phase 7: read af(buf1,mq1); stage B-buf1 (k3 | next k1) h0
#pragma unroll
            for (int t_ = 0; t_ < 4; ++t_)
#pragma unroll
                for (int ks = 0; ks < 2; ++ks) af[t_][ks] = LDA(1, 1, t_, ks);
            if (s) STG(cB, rsB, 1, 1, 0, k3);
            else if (hn) STG(nB, rsB, 1, 1, 0, 1);
            SCHED(); BAR(); SCHED();
            __builtin_amdgcn_s_setprio(1); MM(1, 1); __builtin_amdgcn_s_setprio(0);
            SCHED(); BAR(); SCHED();

            // phase 8: stage B-buf1 h1; MFMA; publish; counted vmcnt
            if (s) STG(cB, rsB, 1, 1, 1, k3);
            else if (hn) STG(nB, rsB, 1, 1, 1, 1);
            SCHED(); BAR(); SCHED();
            __builtin_amdgcn_s_setprio(1); MM(1, 0); __builtin_amdgcn_s_setprio(0);
            if (MODE == 3 && s) LGKM0();
            if (s) asm volatile("s_waitcnt vmcnt(4)" ::: "memory");
            SCHED(); BAR(); SCHED();
        }

        // epilogue for tile tt (scratch in buf1-A region [32768,49152))
        int colb = tcolb[tt] + wn * 64;
        int rowb = trowb[tt] + wm * 128;
        void* out = tout[tt];
        const float* bi_p = tbi[tt];
        int cb = tcb[tt];

        if (MODE == 4) {
            float* ebw = (float*)(smem + 32768) + wave * (16 * ESTRIDE);
            int er = lane >> 4;
            int ec4 = (lane & 15) * 4;
#pragma unroll
            for (int mt = 0; mt < 8; ++mt) {
#pragma unroll
                for (int nt = 0; nt < 4; ++nt) {
                    f32x4 a = acc[mt][nt];
#pragma unroll
                    for (int reg = 0; reg < 4; ++reg)
                        ebw[(quad * 4 + reg) * ESTRIDE + nt * 16 + l15] = a[reg];
                }
#pragma unroll
                for (int j = 0; j < 4; ++j) {
                    int lr = er + 4 * j;
                    f32x2 v0 = *(f32x2*)&ebw[lr * ESTRIDE + ec4];
                    f32x2 v1 = *(f32x2*)&ebw[lr * ESTRIDE + ec4 + 2];
                    int gr = rowb + mt * 16 + lr;
                    int gc = colb + ec4;
                    size_t cidx = (size_t)cb * bsC + (size_t)gr * rsC + gc;
                    float bi = bi_p[gr];
                    float4 xr = *(const float4*)&xres[cidx];
                    float4 st = make_float4(v0.x + bi + xr.x, v0.y + bi + xr.y,
                                            v1.x + bi + xr.z, v1.y + bi + xr.w);
                    *(float4*)&((float*)out)[cidx] = st;
                }
            }
        } else {
            u16* ebw = (smem + 32768) + wave * (16 * ESTRU);
            int er = lane >> 3;
            int ec = (lane & 7) * 8;
            float bcol[4];
            if (MODE == 0) {
#pragma unroll
                for (int nt = 0; nt < 4; ++nt)
                    bcol[nt] = bi_p[colb + nt * 16 + l15];
            }
#pragma unroll
            for (int mt = 0; mt < 8; ++mt) {
                float4 brow;
                if (MODE == 1)
                    brow = *(const float4*)&bi_p[rowb + mt * 16 + quad * 4];
#pragma unroll
                for (int nt = 0; nt < 4; ++nt) {
                    f32x4 a = acc[mt][nt];
#pragma unroll
                    for (int reg = 0; reg < 4; ++reg) {
                        float fv = a[reg];
                        if (MODE == 0) fv += bcol[nt];
                        else if (MODE == 1) fv += ((const float*)&brow)[reg];
                        else if (MODE == 2) fv *= SCALE;
                        ebw[(quad * 4 + reg) * ESTRU + nt * 16 + l15] = f2bf(fv);
                    }
                }
#pragma unroll
                for (int j = 0; j < 2; ++j) {
                    int lr = er + 8 * j;
                    bf16x8 vv = *(const bf16x8*)&ebw[lr * ESTRU + ec];
                    int gr = rowb + mt * 16 + lr;
                    size_t cidx = (size_t)cb * bsC + (size_t)gr * rsC + colb + ec;
                    *(bf16x8*)&((u16*)out)[cidx] = vv;
                }
            }
            // MODE2: per-row softmax partials over this wave's 64 cols
            if (MODE == 2) {
                float* pb = tps_[tt];
                int part = tpart_[tt] + wn;
#pragma unroll
                for (int mt = 0; mt < 8; ++mt) {
#pragma unroll
                    for (int reg = 0; reg < 4; ++reg) {
                        float m = acc[mt][0][reg];
#pragma unroll
                        for (int nt = 1; nt < 4; ++nt) m = fmaxf(m, acc[mt][nt][reg]);
                        m *= SCALE;
#pragma unroll
                        for (int off = 1; off < 16; off <<= 1)
                            m = fmaxf(m, __shfl_xor(m, off));
                        float sm = 0.f;
#pragma unroll
                        for (int nt = 0; nt < 4; ++nt)
                            sm += __expf(acc[mt][nt][reg] * SCALE - m);
#pragma unroll
                        for (int off = 1; off < 16; off <<= 1)
                            sm += __shfl_xor(sm, off);
                        if (l15 == 0) {
                            int gr = rowb + mt * 16 + quad * 4 + reg;
                            f32x2 o; o.x = m; o.y = sm;
                            *(f32x2*)&pb[((size_t)gr * 16 + part) * 2] = o;
                        }
                    }
                }
            }
        }

        if (hn) {
            SCHED();
            // MODE2 epilogue has variable store count -> robust near-drain.
            if (MODE == 2) asm volatile("s_waitcnt vmcnt(4)" ::: "memory");
            else           asm volatile("s_waitcnt vmcnt(20)" ::: "memory");
            BAR(); SCHED();
        }
    }
}

extern "C" void kernel_launch(void* const* d_in, const int* in_sizes, int n_in,
                              void* d_out, int out_size, void* d_ws, size_t ws_size,
                              hipStream_t stream) {
    const float* x    = (const float*)d_in[0];
    const float* gn_w = (const float*)d_in[1];
    const float* gn_b = (const float*)d_in[2];
    const float* wq   = (const float*)d_in[3];
    const float* bq   = (const float*)d_in[4];
    const float* wk   = (const float*)d_in[5];
    const float* bk   = (const float*)d_in[6];
    const float* wv   = (const float*)d_in[7];
    const float* bv   = (const float*)d_in[8];
    const float* wp   = (const float*)d_in[9];
    const float* bp   = (const float*)d_in[10];
    float* y = (float*)d_out;

    const size_t BCN = (size_t)BATCH * C_DIM * N_PIX;
    char* w = (char*)d_ws;
    u16* h  = (u16*)(w);                       // reused as S0
    u16* q  = (u16*)(w + 2 * BCN);             // reused as O0
    u16* k  = (u16*)(w + 4 * BCN);             // reused as O1
    u16* v  = (u16*)(w + 6 * BCN);
    u16* Or = (u16*)(w + 8 * BCN);             // reused as S1
    u16* wb = (u16*)(w + 10 * BCN);            // 2 MB bf16 weights
    u16* wvb = wb + 524288, *wpb = wb + 786432;
    float* stats = (float*)(w + 10 * BCN + 2 * 1024 * 1024);       // 8 KB
    float* pst   = (float*)(w + 10 * BCN + 2 * 1024 * 1024 + 65536);   // 4 MB
    float* sst   = pst + (size_t)32 * 1024 * 16 * 2;                   // 256 KB
    u16* S0 = h;
    u16* S1 = Or;
    u16* O0 = q;
    u16* O1 = k;

    const long long BS = 524288;               // per-batch elems
    const long long SB = 1048576;              // per-batch S elems

    prep_kernel<<<2048, 256, 0, stream>>>(wq, wk, wv, wp, wb, x, stats);
    gnt_kernel<<<512, 256, 0, stream>>>(x, gn_w, gn_b, stats, h);

    // q,k[n][o] = h[n][c]*w[o][c] + b[o]   M=1024 N=512 K=512, 512 tiles
    gemm_kernel<0, 2><<<256, 512, 0, stream>>>(
        h, nullptr, wb, nullptr, q, k, bq, bk, nullptr, nullptr, nullptr,
        512, 512, 512, 512, BS, 0, BS, 2, 4);
    // v[c][n] = wv[c][c']*h[n][c'] + bv[c]  M=512 N=1024 K=512
    gemm_kernel<1, 1><<<256, 512, 0, stream>>>(
        wvb, nullptr, h, nullptr, v, nullptr, bv, nullptr, nullptr, nullptr, nullptr,
        512, 512, 512, 1024, 0, BS, BS, 4, 2);

    // S[i][j] = SCALE * q[i][o]*k[j][o] + row partials  M=N=1024 K=512
    gemm_kernel<2, 2><<<256, 512, 0, stream>>>(
        q, nullptr, k, nullptr, S0, S1, nullptr, nullptr, nullptr, nullptr, pst,
        512, 512, 512, 1024, BS, BS, SB, 4, 4);
    // fold partials -> per-row {M, 1/sum}
    comb_kernel<<<2048, 256, 0, stream>>>(pst, sst);
    // O[i][c] = softmax(S)[i][j]*v[c][j]  M=1024 N=512 K=1024
    gemm_kernel<3, 1><<<256, 512, 0, stream>>>(
        S0, S1, v, nullptr, O0, O1, nullptr, nullptr, nullptr, sst, nullptr,
        1024, 1024, 1024, 512, SB, BS, BS, 2, 4);

    // y[o][n] = x + bp[o] + wp[o][c]*O[n][c]  M=512 N=1024 K=512
    gemm_kernel<4, 1><<<256, 512, 0, stream>>>(
        wpb, nullptr, O0, O1, y, nullptr, bp, nullptr, x, nullptr, nullptr,
        512, 512, 512, 1024, 0, BS, BS, 4, 2);
}

// Round 6
// 356.689 us; speedup vs baseline: 1.2092x; 1.2092x over previous
//
#include <hip/hip_runtime.h>

// AttnBlock B=32, C=512, N=1024. All GEMMs via bf16 MFMA 16x16x32.
// 256x256 tile, BK=64, 8 waves (2M x 4N), 128KB LDS double-buffer,
// 8-phase schedule, counted vmcnt, setprio, XCD-chunked swizzle,
// NT-tile persistence. QKV merged into one NT=3 launch (768 tiles).
// Layouts: h[b][n][c], q[b][n][c], k[b][n][c], v[b][c][n], O[b][n][c].
// GEMM: C[m][n] = sum_k A[m][k]*B[n][k]  (A: MxK rm, B: NxK rm, K-contig)

#define C_DIM 512
#define N_PIX 1024
#define BATCH 32
#define CPG 16
#define EPS 1e-6f
#define SCALE 0.044194173824159216f  // 512^-0.5
#define ESTRIDE 66                   // f32 epilogue LDS row stride (floats)
#define ESTRU   72                   // bf16 epilogue LDS row stride (u16)

typedef unsigned short u16;
typedef __attribute__((ext_vector_type(8))) short bf16x8;
typedef __attribute__((ext_vector_type(4))) float f32x4;
typedef __attribute__((ext_vector_type(2))) float f32x2;

static __device__ __forceinline__ float bf2f(u16 u) {
    union { unsigned int i; float f; } v; v.i = ((unsigned int)u) << 16; return v.f;
}
static __device__ __forceinline__ u16 f2bf(float f) {
    union { float f; unsigned int i; } v; v.f = f;
    unsigned int r = v.i + 0x7fffu + ((v.i >> 16) & 1u);
    return (u16)(r >> 16);
}

static __device__ __forceinline__ void gl_lds16(const u16* g, u16* l) {
    __builtin_amdgcn_global_load_lds(
        (const __attribute__((address_space(1))) unsigned int*)g,
        (__attribute__((address_space(3))) unsigned int*)l,
        16, 0, 0);
}

#define BAR()   __builtin_amdgcn_s_barrier()
#define SCHED() __builtin_amdgcn_sched_barrier(0x7)

// ------------------------------------------------- weights->bf16 + GN stats
__global__ __launch_bounds__(256) void prep_kernel(
        const float* __restrict__ wq, const float* __restrict__ wk,
        const float* __restrict__ wv, const float* __restrict__ wp,
        u16* __restrict__ out, const float* __restrict__ x,
        float* __restrict__ stats) {
    int blk = blockIdx.x;
    if (blk < 1024) {   // weight convert
        int i = blk * 256 + threadIdx.x;
        int mat = i >> 16;
        const float* src = (mat == 0) ? wq : (mat == 1) ? wk : (mat == 2) ? wv : wp;
        float4 v = ((const float4*)src)[i & 65535];
        ushort4 o;
        o.x = f2bf(v.x); o.y = f2bf(v.y); o.z = f2bf(v.z); o.w = f2bf(v.w);
        *(ushort4*)&out[(size_t)i * 4] = o;
        return;
    }
    blk -= 1024;        // group-norm stats for (b,g)
    int b = blk >> 5, g = blk & 31;
    const float4* xv = (const float4*)(x + ((size_t)(b * C_DIM + g * CPG)) * N_PIX);
    int tid = threadIdx.x;
    float s = 0.f, sq = 0.f;
#pragma unroll 4
    for (int i = tid; i < (CPG * N_PIX) / 4; i += 256) {
        float4 v = xv[i];
        s  += v.x + v.y + v.z + v.w;
        sq += v.x * v.x + v.y * v.y + v.z * v.z + v.w * v.w;
    }
#pragma unroll
    for (int m = 1; m < 64; m <<= 1) {
        s += __shfl_xor(s, m);
        sq += __shfl_xor(sq, m);
    }
    __shared__ float rs[4], rq[4];
    int wv_ = tid >> 6;
    if ((tid & 63) == 0) { rs[wv_] = s; rq[wv_] = sq; }
    __syncthreads();
    if (tid == 0) {
        float S = rs[0] + rs[1] + rs[2] + rs[3];
        float Q = rq[0] + rq[1] + rq[2] + rq[3];
        float mean = S * (1.0f / (CPG * N_PIX));
        float var  = Q * (1.0f / (CPG * N_PIX)) - mean * mean;
        stats[blk * 2] = mean;
        stats[blk * 2 + 1] = rsqrtf(var + EPS);
    }
}

// ------------------------------------------------- GN transform (coalesced)
__global__ __launch_bounds__(256) void gnt_kernel(
        const float* __restrict__ x, const float* __restrict__ gw,
        const float* __restrict__ gb, const float* __restrict__ stats,
        u16* __restrict__ h) {
    int blk = blockIdx.x;
    int b = blk >> 4, nc = blk & 15;
    int n0 = nc * 64;
    __shared__ u16 T[64 * 520];
    int tid = threadIdx.x;
    int cq = tid >> 4;
    int n4 = tid & 15;
    const float* xb = x + (size_t)b * C_DIM * N_PIX + n0;
#pragma unroll 4
    for (int pass = 0; pass < 32; ++pass) {
        int c = pass * 16 + cq;
        int g = c >> 4;
        float mean = stats[(b * 32 + g) * 2];
        float inv  = stats[(b * 32 + g) * 2 + 1];
        float sc = gw[c] * inv;
        float sh = gb[c] - mean * sc;
        float4 v = *(const float4*)(xb + (size_t)c * N_PIX + n4 * 4);
        int nn = n4 * 4;
        T[(nn + 0) * 520 + c] = f2bf(v.x * sc + sh);
        T[(nn + 1) * 520 + c] = f2bf(v.y * sc + sh);
        T[(nn + 2) * 520 + c] = f2bf(v.z * sc + sh);
        T[(nn + 3) * 520 + c] = f2bf(v.w * sc + sh);
    }
    __syncthreads();
    u16* hb = h + ((size_t)b * N_PIX + n0) * C_DIM;
    int rr = tid >> 5;
    int cc = (tid & 31) * 16;
#pragma unroll
    for (int p = 0; p < 8; ++p) {
        int n = p * 8 + rr;
        bf16x8 v0 = *(const bf16x8*)&T[n * 520 + cc];
        bf16x8 v1 = *(const bf16x8*)&T[n * 520 + cc + 8];
        *(bf16x8*)&hb[(size_t)n * C_DIM + cc] = v0;
        *(bf16x8*)&hb[(size_t)n * C_DIM + cc + 8] = v1;
    }
}

// ------------------------------------------------------------- MFMA GEMM
// MODE 0: merged qkv, NT=3, 768 tiles. t<512: q/k (bias[col], bf16);
//         t>=512: v (bias[row], bf16, rsC=1024).
// MODE 2: scores (S0/S1 halves), bf16 out *SCALE
// MODE 3: pv (A=S0/S1, out=O0/O1), bf16 out
// MODE 4: proj (B=O0/O1), f32 out +bias[row]+resid

#define MM(mq, nq) do { \
    _Pragma("unroll") \
    for (int t_ = 0; t_ < 4; ++t_) { \
        _Pragma("unroll") \
        for (int n_ = 0; n_ < 2; ++n_) { \
            _Pragma("unroll") \
            for (int ks_ = 0; ks_ < 2; ++ks_) \
                acc[(mq)*4 + t_][(nq)*2 + n_] = \
                    __builtin_amdgcn_mfma_f32_16x16x32_bf16( \
                        af[t_][ks_], bf[(nq)*2 + n_][ks_], \
                        acc[(mq)*4 + t_][(nq)*2 + n_], 0, 0, 0); \
        } \
    } \
} while (0)

struct TileDesc {
    const u16* gA; const u16* gB;
    void* out; const float* bi;
    int cb, colb, rowb, rsC, cm;   // cm: 0=bias-col bf16, 1=bias-row bf16
};

template <int MODE, int NT>
__global__ __launch_bounds__(512, 2) void gemm_kernel(
        const u16* __restrict__ A, const u16* __restrict__ A2,
        const u16* __restrict__ B, const u16* __restrict__ B2,
        void* __restrict__ Cv, void* __restrict__ Cv2, void* __restrict__ Cv3,
        const float* __restrict__ bias, const float* __restrict__ bias2,
        const float* __restrict__ bias3, const float* __restrict__ xres,
        int K, int rsA, int rsB, int rsC,
        long long bsA, long long bsB, long long bsC,
        int nx, int ny) {
    const int nwg = 256 * NT;

    auto decode = [&](int flat) -> TileDesc {
        TileDesc d;
        int t = (flat & 7) * (nwg >> 3) + (flat >> 3);   // XCD-chunked swizzle
        if (MODE == 0) {
            if (t < 512) {            // q/k: M=1024 N=512 K=512, z=2b+mat
                int bx = t & 1, by = (t >> 1) & 3, bz = t >> 3;
                int mat = bz & 1, b = bz >> 1;
                d.gA = A + (size_t)b * bsA + (size_t)by * 256 * rsA;       // h
                d.gB = B + (size_t)mat * 262144 + (size_t)bx * 256 * rsB;  // wq/wk
                d.out = mat ? Cv2 : Cv;
                d.bi = mat ? bias2 : bias;
                d.cb = b; d.colb = bx * 256; d.rowb = by * 256;
                d.rsC = 512; d.cm = 0;
            } else {                  // v: M=512 N=1024 K=512
                int t2 = t - 512;
                int bx = t2 & 3, by = (t2 >> 2) & 1, bz = t2 >> 3;
                d.gA = A2 + (size_t)by * 256 * rsA;                        // wv
                d.gB = B2 + (size_t)bz * bsB + (size_t)bx * 256 * rsB;     // h
                d.out = Cv3; d.bi = bias3;
                d.cb = bz; d.colb = bx * 256; d.rowb = by * 256;
                d.rsC = 1024; d.cm = 1;
            }
            return d;
        }
        int bx = t % nx, by = (t / nx) % ny, bz = t / (nx * ny);
        int b = bz;
        d.rsC = rsC; d.cm = 0;
        if (MODE == 2) {
            d.gA = A + (size_t)b * bsA + (size_t)by * 256 * rsA;
            d.gB = B + (size_t)b * bsB + (size_t)bx * 256 * rsB;
            d.out = (b >= 16) ? Cv2 : Cv; d.bi = nullptr;
        } else if (MODE == 3) {
            d.gA = ((b >= 16) ? A2 : A) + (size_t)(b & 15) * bsA + (size_t)by * 256 * rsA;
            d.gB = B + (size_t)b * bsB + (size_t)bx * 256 * rsB;
            d.out = (b >= 16) ? Cv2 : Cv; d.bi = nullptr;
        } else {  // MODE 4
            d.gA = A + (size_t)by * 256 * rsA;
            d.gB = ((b >= 16) ? B2 : B) + (size_t)(b & 15) * bsB + (size_t)bx * 256 * rsB;
            d.out = Cv; d.bi = bias;
        }
        d.cb = (MODE == 2 || MODE == 3) ? (b & 15) : b;
        d.colb = bx * 256; d.rowb = by * 256;
        return d;
    };

    // 128 KB: [0,16K)=A0 [16K,32K)=B0 [32K,48K)=A1 [48K,64K)=B1  (u16 idx)
    __shared__ __align__(16) u16 smem[65536];

    int tid = threadIdx.x;
    int lane = tid & 63, wave = tid >> 6;
    int wm = wave >> 2, wn = wave & 3;
    int quad = lane >> 4, l15 = lane & 15, l7 = lane & 7;
    int srow = tid >> 3;
    int lg = (tid & 7) ^ (srow & 7);

    const int nk = K >> 6;
    const int nit = nk >> 1;

    auto STG = [&](const u16* g, int rs, int buf, int isB, int hh, int kt) {
        const u16* src = g + (size_t)(hh * 128 + srow) * rs + (size_t)kt * 64 + lg * 8;
        u16* dst = &smem[buf * 32768 + isB * 16384 + (hh * 128 + srow) * 64 + (tid & 7) * 8];
        gl_lds16(src, dst);
        gl_lds16(src + (size_t)64 * rs, dst + 4096);
    };
    auto LDA = [&](int buf, int mq, int t_, int ks) -> bf16x8 {
        return *(const bf16x8*)&smem[buf * 32768 +
            (wm * 128 + mq * 64 + t_ * 16 + l15) * 64 + (((ks * 4 + quad) ^ l7) << 3)];
    };
    auto LDB = [&](int buf, int nt, int ks) -> bf16x8 {
        return *(const bf16x8*)&smem[buf * 32768 + 16384 +
            (wn * 64 + nt * 16 + l15) * 64 + (((ks * 4 + quad) ^ l7) << 3)];
    };

    f32x4 acc[8][4];
    bf16x8 af[4][2], bf[4][2];

    TileDesc cur = decode(blockIdx.x);

#pragma unroll
    for (int tt = 0; tt < NT; ++tt) {
        const bool hn = (tt + 1 < NT);
        TileDesc nxt = hn ? decode(blockIdx.x + (tt + 1) * 256) : cur;
        const u16* cA = cur.gA;
        const u16* cB = cur.gB;
        const u16* nA = nxt.gA;
        const u16* nB = nxt.gB;

        if (tt == 0) {
            // cold prologue: buf0 full (tile k0), buf1 B-halves (k1)
            STG(cB, rsB, 0, 1, 0, 0); STG(cB, rsB, 0, 1, 1, 0);
            STG(cA, rsA, 0, 0, 0, 0); STG(cA, rsA, 0, 0, 1, 0);
            STG(cB, rsB, 1, 1, 0, 1); STG(cB, rsB, 1, 1, 1, 1);
            asm volatile("s_waitcnt vmcnt(4)" ::: "memory");
            SCHED(); BAR(); SCHED();
        }

#pragma unroll
        for (int mt = 0; mt < 8; ++mt)
#pragma unroll
            for (int nt = 0; nt < 4; ++nt)
                acc[mt][nt] = (f32x4){0.f, 0.f, 0.f, 0.f};

        for (int it = 0; it < nit; ++it) {
            const bool s = (it + 1 < nit);
            const int k1 = 2 * it + 1, k2 = 2 * it + 2, k3 = 2 * it + 3;

            // phase 1: read af(buf0,mq0)+bf(n0,1); stage A-buf1 (k1) h0
#pragma unroll
            for (int t_ = 0; t_ < 4; ++t_)
#pragma unroll
                for (int ks = 0; ks < 2; ++ks) af[t_][ks] = LDA(0, 0, t_, ks);
#pragma unroll
            for (int n = 0; n < 2; ++n)
#pragma unroll
                for (int ks = 0; ks < 2; ++ks) bf[n][ks] = LDB(0, n, ks);
            STG(cA, rsA, 1, 0, 0, k1);
            SCHED(); BAR(); SCHED();
            __builtin_amdgcn_s_setprio(1); MM(0, 0); __builtin_amdgcn_s_setprio(0);
            SCHED(); BAR(); SCHED();

            // phase 2: read bf(n2,3) buf0; stage A-buf1 (k1) h1
#pragma unroll
            for (int n = 2; n < 4; ++n)
#pragma unroll
                for (int ks = 0; ks < 2; ++ks) bf[n][ks] = LDB(0, n, ks);
            STG(cA, rsA, 1, 0, 1, k1);
            SCHED(); BAR(); SCHED();
            __builtin_amdgcn_s_setprio(1); MM(0, 1); __builtin_amdgcn_s_setprio(0);
            SCHED(); BAR(); SCHED();

            // phase 3: read af(buf0,mq1); stage B-buf0 (k2 | next k0) h0
#pragma unroll
            for (int t_ = 0; t_ < 4; ++t_)
#pragma unroll
                for (int ks = 0; ks < 2; ++ks) af[t_][ks] = LDA(0, 1, t_, ks);
            if (s) STG(cB, rsB, 0, 1, 0, k2);
            else if (hn) STG(nB, rsB, 0, 1, 0, 0);
            SCHED(); BAR(); SCHED();
            __builtin_amdgcn_s_setprio(1); MM(1, 1); __builtin_amdgcn_s_setprio(0);
            SCHED(); BAR(); SCHED();

            // phase 4: stage B-buf0 h1; MFMA; counted vmcnt -> buf1 ready
            if (s) STG(cB, rsB, 0, 1, 1, k2);
            else if (hn) STG(nB, rsB, 0, 1, 1, 0);
            SCHED(); BAR(); SCHED();
            __builtin_amdgcn_s_setprio(1); MM(1, 0); __builtin_amdgcn_s_setprio(0);
            if (s || hn) asm volatile("s_waitcnt vmcnt(4)" ::: "memory");
            else         asm volatile("s_waitcnt vmcnt(0)" ::: "memory");
            SCHED(); BAR(); SCHED();

            // phase 5: read af(buf1,mq0)+bf(n0,1); stage A-buf0 (k2|next k0)
#pragma unroll
            for (int t_ = 0; t_ < 4; ++t_)
#pragma unroll
                for (int ks = 0; ks < 2; ++ks) af[t_][ks] = LDA(1, 0, t_, ks);
#pragma unroll
            for (int n = 0; n < 2; ++n)
#pragma unroll
                for (int ks = 0; ks < 2; ++ks) bf[n][ks] = LDB(1, n, ks);
            if (s) STG(cA, rsA, 0, 0, 0, k2);
            else if (hn) STG(nA, rsA, 0, 0, 0, 0);
            SCHED(); BAR(); SCHED();
            __builtin_amdgcn_s_setprio(1); MM(0, 0); __builtin_amdgcn_s_setprio(0);
            SCHED(); BAR(); SCHED();

            // phase 6: read bf(n2,3) buf1; stage A-buf0 h1
#pragma unroll
            for (int n = 2; n < 4; ++n)
#pragma unroll
                for (int ks = 0; ks < 2; ++ks) bf[n][ks] = LDB(1, n, ks);
            if (s) STG(cA, rsA, 0, 0, 1, k2);
            else if (hn) STG(nA, rsA, 0, 0, 1, 0);
            SCHED(); BAR(); SCHED();
            __builtin_amdgcn_s_setprio(1); MM(0, 1); __builtin_amdgcn_s_setprio(0);
            SCHED(); BAR(); SCHED();

            // phase 7: read af(buf1,mq1); stage B-buf1 (k3 | next k1) h0
#pragma unroll
            for (int t_ = 0; t_ < 4; ++t_)
#pragma unroll
                for (int ks = 0; ks < 2; ++ks) af[t_][ks] = LDA(1, 1, t_, ks);
            if (s) STG(cB, rsB, 1, 1, 0, k3);
            else if (hn) STG(nB, rsB, 1, 1, 0, 1);
            SCHED(); BAR(); SCHED();
            __builtin_amdgcn_s_setprio(1); MM(1, 1); __builtin_amdgcn_s_setprio(0);
            SCHED(); BAR(); SCHED();

            // phase 8: stage B-buf1 h1; MFMA; counted vmcnt (steady only)
            if (s) STG(cB, rsB, 1, 1, 1, k3);
            else if (hn) STG(nB, rsB, 1, 1, 1, 1);
            SCHED(); BAR(); SCHED();
            __builtin_amdgcn_s_setprio(1); MM(1, 0); __builtin_amdgcn_s_setprio(0);
            if (s) asm volatile("s_waitcnt vmcnt(4)" ::: "memory");
            SCHED(); BAR(); SCHED();
        }

        // epilogue for tile tt (scratch in buf1-A region [32768,49152))
        int colb = cur.colb + wn * 64;
        int rowb = cur.rowb + wm * 128;
        void* out = cur.out;
        const float* bi_p = cur.bi;
        int cb = cur.cb;
        int rsCt = cur.rsC;

        if (MODE == 4) {
            float* ebw = (float*)(smem + 32768) + wave * (16 * ESTRIDE);
            int er = lane >> 4;
            int ec4 = (lane & 15) * 4;
#pragma unroll
            for (int mt = 0; mt < 8; ++mt) {
#pragma unroll
                for (int nt = 0; nt < 4; ++nt) {
                    f32x4 a = acc[mt][nt];
#pragma unroll
                    for (int reg = 0; reg < 4; ++reg)
                        ebw[(quad * 4 + reg) * ESTRIDE + nt * 16 + l15] = a[reg];
                }
#pragma unroll
                for (int j = 0; j < 4; ++j) {
                    int lr = er + 4 * j;
                    f32x2 v0 = *(f32x2*)&ebw[lr * ESTRIDE + ec4];
                    f32x2 v1 = *(f32x2*)&ebw[lr * ESTRIDE + ec4 + 2];
                    int gr = rowb + mt * 16 + lr;
                    int gc = colb + ec4;
                    size_t cidx = (size_t)cb * bsC + (size_t)gr * rsCt + gc;
                    float bi = bi_p[gr];
                    float4 xr = *(const float4*)&xres[cidx];
                    float4 st = make_float4(v0.x + bi + xr.x, v0.y + bi + xr.y,
                                            v1.x + bi + xr.z, v1.y + bi + xr.w);
                    *(float4*)&((float*)out)[cidx] = st;
                }
            }
        } else {
            u16* ebw = (smem + 32768) + wave * (16 * ESTRU);
            int er = lane >> 3;
            int ec = (lane & 7) * 8;
            float bcol[4];
            if (MODE == 0 && cur.cm == 0) {
#pragma unroll
                for (int nt = 0; nt < 4; ++nt)
                    bcol[nt] = bi_p[colb + nt * 16 + l15];
            }
#pragma unroll
            for (int mt = 0; mt < 8; ++mt) {
                float4 brow = make_float4(0.f, 0.f, 0.f, 0.f);
                if (MODE == 0 && cur.cm == 1)
                    brow = *(const float4*)&bi_p[rowb + mt * 16 + quad * 4];
#pragma unroll
                for (int nt = 0; nt < 4; ++nt) {
                    f32x4 a = acc[mt][nt];
#pragma unroll
                    for (int reg = 0; reg < 4; ++reg) {
                        float fv = a[reg];
                        if (MODE == 0) {
                            if (cur.cm == 0) fv += bcol[nt];
                            else fv += ((const float*)&brow)[reg];
                        } else if (MODE == 2) fv *= SCALE;
                        ebw[(quad * 4 + reg) * ESTRU + nt * 16 + l15] = f2bf(fv);
                    }
                }
#pragma unroll
                for (int j = 0; j < 2; ++j) {
                    int lr = er + 8 * j;
                    bf16x8 vv = *(const bf16x8*)&ebw[lr * ESTRU + ec];
                    int gr = rowb + mt * 16 + lr;
                    size_t cidx = (size_t)cb * bsC + (size_t)gr * rsCt + colb + ec;
                    *(bf16x8*)&((u16*)out)[cidx] = vv;
                }
            }
        }

        if (hn) {
            // junction: oldest 8 of {12 junction loads + 16 epilogue stores}
            // must land -> vmcnt(20) covers buf0 A/B; buf1-B loads are
            // covered by next tile's phase-4 vmcnt(4). Barrier so every
            // wave's wait is observed before buf1-A is overwritten.
            SCHED();
            asm volatile("s_waitcnt vmcnt(20)" ::: "memory");
            BAR(); SCHED();
        }
        cur = nxt;
    }
}

// ------------------------------------------------------------- Softmax
// bf16 S row (1024) -> bf16 P in place. wave-per-row, 4 rows/block.
__global__ __launch_bounds__(256) void softmax_kernel(
        u16* __restrict__ S0, u16* __restrict__ S1) {
    int row = blockIdx.x * 4 + (threadIdx.x >> 6);
    int lane = threadIdx.x & 63;
    u16* p = ((row & 16384) ? S1 : S0) + (size_t)(row & 16383) * N_PIX + lane * 16;
    bf16x8 u0 = *(const bf16x8*)p;
    bf16x8 u1 = *(const bf16x8*)(p + 8);
    float f[16];
#pragma unroll
    for (int i = 0; i < 8; ++i) {
        f[i] = bf2f((u16)u0[i]);
        f[8 + i] = bf2f((u16)u1[i]);
    }
    float m = f[0];
#pragma unroll
    for (int i = 1; i < 16; ++i) m = fmaxf(m, f[i]);
#pragma unroll
    for (int off = 1; off < 64; off <<= 1) m = fmaxf(m, __shfl_xor(m, off));
    float s = 0.f;
#pragma unroll
    for (int i = 0; i < 16; ++i) { f[i] = __expf(f[i] - m); s += f[i]; }
#pragma unroll
    for (int off = 1; off < 64; off <<= 1) s += __shfl_xor(s, off);
    float inv = 1.0f / s;
    bf16x8 s0, s1;
#pragma unroll
    for (int i = 0; i < 8; ++i) {
        s0[i] = (short)f2bf(f[i] * inv);
        s1[i] = (short)f2bf(f[8 + i] * inv);
    }
    *(bf16x8*)p = s0;
    *(bf16x8*)(p + 8) = s1;
}

extern "C" void kernel_launch(void* const* d_in, const int* in_sizes, int n_in,
                              void* d_out, int out_size, void* d_ws, size_t ws_size,
                              hipStream_t stream) {
    const float* x    = (const float*)d_in[0];
    const float* gn_w = (const float*)d_in[1];
    const float* gn_b = (const float*)d_in[2];
    const float* wq   = (const float*)d_in[3];
    const float* bq   = (const float*)d_in[4];
    const float* wk   = (const float*)d_in[5];
    const float* bk   = (const float*)d_in[6];
    const float* wv   = (const float*)d_in[7];
    const float* bv   = (const float*)d_in[8];
    const float* wp   = (const float*)d_in[9];
    const float* bp   = (const float*)d_in[10];
    float* y = (float*)d_out;

    const size_t BCN = (size_t)BATCH * C_DIM * N_PIX;
    char* w = (char*)d_ws;
    u16* h  = (u16*)(w);                       // reused as S0
    u16* q  = (u16*)(w + 2 * BCN);             // reused as O0
    u16* k  = (u16*)(w + 4 * BCN);             // reused as O1
    u16* v  = (u16*)(w + 6 * BCN);
    u16* Or = (u16*)(w + 8 * BCN);             // reused as S1
    u16* wb = (u16*)(w + 10 * BCN);            // 2 MB bf16 weights
    u16* wvb = wb + 524288, *wpb = wb + 786432;
    float* stats = (float*)(w + 10 * BCN + 2 * 1024 * 1024);   // 8 KB
    u16* S0 = h;
    u16* S1 = Or;
    u16* O0 = q;
    u16* O1 = k;

    const long long BS = 524288;               // per-batch elems
    const long long SB = 1048576;              // per-batch S elems

    prep_kernel<<<2048, 256, 0, stream>>>(wq, wk, wv, wp, wb, x, stats);
    gnt_kernel<<<512, 256, 0, stream>>>(x, gn_w, gn_b, stats, h);

    // merged q,k,v: 768 tiles, NT=3
    // q,k[n][o] = h[n][c]*w[o][c]+b[o]; v[c][n] = wv[c][c']*h[n][c']+bv[c]
    gemm_kernel<0, 3><<<256, 512, 0, stream>>>(
        h, wvb, wb, h, q, k, v, bq, bk, bv, nullptr,
        512, 512, 512, 512, BS, BS, BS, 0, 0);

    // S[i][j] = SCALE * q[i][o]*k[j][o]  M=N=1024 K=512, 512 tiles
    gemm_kernel<2, 2><<<256, 512, 0, stream>>>(
        q, nullptr, k, nullptr, S0, S1, nullptr, nullptr, nullptr, nullptr, nullptr,
        512, 512, 512, 1024, BS, BS, SB, 4, 4);
    softmax_kernel<<<8192, 256, 0, stream>>>(S0, S1);
    // O[i][c] = P[i][j]*v[c][j]  M=1024 N=512 K=1024
    gemm_kernel<3, 1><<<256, 512, 0, stream>>>(
        S0, S1, v, nullptr, O0, O1, nullptr, nullptr, nullptr, nullptr, nullptr,
        1024, 1024, 1024, 512, SB, BS, BS, 2, 4);

    // y[o][n] = x + bp[o] + wp[o][c]*O[n][c]  M=512 N=1024 K=512
    gemm_kernel<4, 1><<<256, 512, 0, stream>>>(
        wpb, nullptr, O0, O1, y, nullptr, nullptr, bp, nullptr, nullptr, x,
        512, 512, 512, 1024, 0, BS, BS, 4, 2);
}

// Round 7
// 337.604 us; speedup vs baseline: 1.2776x; 1.0565x over previous
//
#include <hip/hip_runtime.h>

// AttnBlock B=32, C=512, N=1024. bf16 MFMA 16x16x32.
// Heavy GEMMs (q/k, scores): gemm32 = 256x128 tile, BK=32, 48KB LDS,
// 4-phase counted-vmcnt schedule, 2 blocks/CU (16 waves) for cross-block
// stall overlap. Other GEMMs: proven 256x256 BK=64 single-tile template.
// Layouts: h[b][n][c], q[b][n][c], k[b][n][c], v[b][c][n], O[b][n][c].
// GEMM: C[m][n] = sum_k A[m][k]*B[n][k]  (A: MxK rm, B: NxK rm, K-contig)

#define C_DIM 512
#define N_PIX 1024
#define BATCH 32
#define CPG 16
#define EPS 1e-6f
#define SCALE 0.044194173824159216f  // 512^-0.5
#define ESTRIDE 66                   // f32 epilogue LDS row stride (floats)
#define ESTRU   72                   // bf16 epilogue LDS row stride (u16)
#define ES2     40                   // gemm32 epilogue LDS row stride (u16)

typedef unsigned short u16;
typedef __attribute__((ext_vector_type(8))) short bf16x8;
typedef __attribute__((ext_vector_type(4))) float f32x4;
typedef __attribute__((ext_vector_type(2))) float f32x2;

static __device__ __forceinline__ float bf2f(u16 u) {
    union { unsigned int i; float f; } v; v.i = ((unsigned int)u) << 16; return v.f;
}
static __device__ __forceinline__ u16 f2bf(float f) {
    union { float f; unsigned int i; } v; v.f = f;
    unsigned int r = v.i + 0x7fffu + ((v.i >> 16) & 1u);
    return (u16)(r >> 16);
}

static __device__ __forceinline__ void gl_lds16(const u16* g, u16* l) {
    __builtin_amdgcn_global_load_lds(
        (const __attribute__((address_space(1))) unsigned int*)g,
        (__attribute__((address_space(3))) unsigned int*)l,
        16, 0, 0);
}

#define BAR()   __builtin_amdgcn_s_barrier()
#define SCHED() __builtin_amdgcn_sched_barrier(0x7)

// ------------------------------------------------- weights->bf16 + GN stats
__global__ __launch_bounds__(256) void prep_kernel(
        const float* __restrict__ wq, const float* __restrict__ wk,
        const float* __restrict__ wv, const float* __restrict__ wp,
        u16* __restrict__ out, const float* __restrict__ x,
        float* __restrict__ stats) {
    int blk = blockIdx.x;
    if (blk < 1024) {   // weight convert
        int i = blk * 256 + threadIdx.x;
        int mat = i >> 16;
        const float* src = (mat == 0) ? wq : (mat == 1) ? wk : (mat == 2) ? wv : wp;
        float4 v = ((const float4*)src)[i & 65535];
        ushort4 o;
        o.x = f2bf(v.x); o.y = f2bf(v.y); o.z = f2bf(v.z); o.w = f2bf(v.w);
        *(ushort4*)&out[(size_t)i * 4] = o;
        return;
    }
    blk -= 1024;        // group-norm stats for (b,g)
    int b = blk >> 5, g = blk & 31;
    const float4* xv = (const float4*)(x + ((size_t)(b * C_DIM + g * CPG)) * N_PIX);
    int tid = threadIdx.x;
    float s = 0.f, sq = 0.f;
#pragma unroll 4
    for (int i = tid; i < (CPG * N_PIX) / 4; i += 256) {
        float4 v = xv[i];
        s  += v.x + v.y + v.z + v.w;
        sq += v.x * v.x + v.y * v.y + v.z * v.z + v.w * v.w;
    }
#pragma unroll
    for (int m = 1; m < 64; m <<= 1) {
        s += __shfl_xor(s, m);
        sq += __shfl_xor(sq, m);
    }
    __shared__ float rs[4], rq[4];
    int wv_ = tid >> 6;
    if ((tid & 63) == 0) { rs[wv_] = s; rq[wv_] = sq; }
    __syncthreads();
    if (tid == 0) {
        float S = rs[0] + rs[1] + rs[2] + rs[3];
        float Q = rq[0] + rq[1] + rq[2] + rq[3];
        float mean = S * (1.0f / (CPG * N_PIX));
        float var  = Q * (1.0f / (CPG * N_PIX)) - mean * mean;
        stats[blk * 2] = mean;
        stats[blk * 2 + 1] = rsqrtf(var + EPS);
    }
}

// ------------------------------------------------- GN transform (coalesced)
__global__ __launch_bounds__(256) void gnt_kernel(
        const float* __restrict__ x, const float* __restrict__ gw,
        const float* __restrict__ gb, const float* __restrict__ stats,
        u16* __restrict__ h) {
    int blk = blockIdx.x;
    int b = blk >> 4, nc = blk & 15;
    int n0 = nc * 64;
    __shared__ u16 T[64 * 520];
    int tid = threadIdx.x;
    int cq = tid >> 4;
    int n4 = tid & 15;
    const float* xb = x + (size_t)b * C_DIM * N_PIX + n0;
#pragma unroll 4
    for (int pass = 0; pass < 32; ++pass) {
        int c = pass * 16 + cq;
        int g = c >> 4;
        float mean = stats[(b * 32 + g) * 2];
        float inv  = stats[(b * 32 + g) * 2 + 1];
        float sc = gw[c] * inv;
        float sh = gb[c] - mean * sc;
        float4 v = *(const float4*)(xb + (size_t)c * N_PIX + n4 * 4);
        int nn = n4 * 4;
        T[(nn + 0) * 520 + c] = f2bf(v.x * sc + sh);
        T[(nn + 1) * 520 + c] = f2bf(v.y * sc + sh);
        T[(nn + 2) * 520 + c] = f2bf(v.z * sc + sh);
        T[(nn + 3) * 520 + c] = f2bf(v.w * sc + sh);
    }
    __syncthreads();
    u16* hb = h + ((size_t)b * N_PIX + n0) * C_DIM;
    int rr = tid >> 5;
    int cc = (tid & 31) * 16;
#pragma unroll
    for (int p = 0; p < 8; ++p) {
        int n = p * 8 + rr;
        bf16x8 v0 = *(const bf16x8*)&T[n * 520 + cc];
        bf16x8 v1 = *(const bf16x8*)&T[n * 520 + cc + 8];
        *(bf16x8*)&hb[(size_t)n * C_DIM + cc] = v0;
        *(bf16x8*)&hb[(size_t)n * C_DIM + cc + 8] = v1;
    }
}

// ------------------------------------------------------------- gemm32
// 256x128 tile, BK=32, 8 waves (2M x 4N, per-wave 128x32), 48KB LDS,
// 4 phases / 2 K-tiles, counted vmcnt(1), 2 blocks/CU.
// MODE 0: q&k (bias[col]); MODE 2: scores (*SCALE, S0/S1 halves)

#define MM32(mq) do { \
    _Pragma("unroll") \
    for (int t_ = 0; t_ < 4; ++t_) { \
        _Pragma("unroll") \
        for (int n_ = 0; n_ < 2; ++n_) \
            acc[(mq)*4 + t_][n_] = \
                __builtin_amdgcn_mfma_f32_16x16x32_bf16( \
                    af[t_], bf[n_], acc[(mq)*4 + t_][n_], 0, 0, 0); \
    } \
} while (0)

template <int MODE>
__global__ __launch_bounds__(512, 4) void gemm32_kernel(
        const u16* __restrict__ A, const u16* __restrict__ B,
        void* __restrict__ Cv, void* __restrict__ Cv2,
        const float* __restrict__ bias, const float* __restrict__ bias2,
        int K, int rsA, int rsB, int rsC,
        long long bsA, long long bsB, long long bsC) {
    // XCD-chunked bijective swizzle, nwg = 1024
    int flat = blockIdx.x;
    int t = (flat & 7) * 128 + (flat >> 3);

    const u16 *gA, *gB;
    void* out;
    const float* bi_p;
    int cb, colb, rowb;
    if (MODE == 0) {            // q/k: M=1024 N=512, 4x4x(32*2) tiles
        int bx = t & 3, by = (t >> 2) & 3, z = t >> 4;
        int mat = z & 1, b = z >> 1;
        gA = A + (size_t)b * bsA + (size_t)by * 256 * rsA;        // h
        gB = B + (size_t)mat * 262144 + (size_t)bx * 128 * rsB;   // wq/wk
        out = mat ? Cv2 : Cv;
        bi_p = mat ? bias2 : bias;
        cb = b; colb = bx * 128; rowb = by * 256;
    } else {                    // scores: M=1024 N=1024, 4x8x32 tiles
        int bx = t & 7, by = (t >> 3) & 3, b = t >> 5;
        gA = A + (size_t)b * bsA + (size_t)by * 256 * rsA;        // q
        gB = B + (size_t)b * bsB + (size_t)bx * 128 * rsB;        // k
        out = (b >= 16) ? Cv2 : Cv;
        bi_p = nullptr;
        cb = b & 15; colb = bx * 128; rowb = by * 256;
    }

    // 48 KB LDS (u16 idx): buf*12288 + {A:0..8192, B:8192..12288}
    __shared__ __align__(16) u16 smem[24576];

    int tid = threadIdx.x;
    int lane = tid & 63, wave = tid >> 6;
    int wm = wave >> 2, wn = wave & 3;            // 2M x 4N
    int quad = lane >> 4, l15 = lane & 15;
    int srow = tid >> 2;                          // 0..127 staging row
    int lg = (tid & 3) ^ ((srow >> 1) & 3);       // pre-swizzled src group

    const int nk = K >> 5;                        // 32-wide K-tiles
    const int nit = nk >> 1;

    // stage A half-tile (128 rows x 32): 1 gl_lds/thread
    auto STGA = [&](int buf, int hh, int kt) {
        const u16* src = gA + (size_t)(hh * 128 + srow) * rsA + (size_t)kt * 32 + lg * 8;
        u16* dst = &smem[buf * 12288 + (hh * 128 + srow) * 32 + (tid & 3) * 8];
        gl_lds16(src, dst);
    };
    // stage B tile (128 rows x 32): 1 gl_lds/thread
    auto STGB = [&](int buf, int kt) {
        const u16* src = gB + (size_t)srow * rsB + (size_t)kt * 32 + lg * 8;
        u16* dst = &smem[buf * 12288 + 8192 + srow * 32 + (tid & 3) * 8];
        gl_lds16(src, dst);
    };
    // fragment reads: k-octet = quad, swizzled by ((row>>1)&3)
    auto LDA32 = [&](int buf, int mq, int t_) -> bf16x8 {
        int r = wm * 128 + mq * 64 + t_ * 16 + l15;
        return *(const bf16x8*)&smem[buf * 12288 + r * 32 +
                                     ((quad ^ ((r >> 1) & 3)) << 3)];
    };
    auto LDB32 = [&](int buf, int nt) -> bf16x8 {
        int r = wn * 32 + nt * 16 + l15;
        return *(const bf16x8*)&smem[buf * 12288 + 8192 + r * 32 +
                                     ((quad ^ ((r >> 1) & 3)) << 3)];
    };

    f32x4 acc[8][2];
#pragma unroll
    for (int mt = 0; mt < 8; ++mt)
#pragma unroll
        for (int nt = 0; nt < 2; ++nt)
            acc[mt][nt] = (f32x4){0.f, 0.f, 0.f, 0.f};
    bf16x8 af[4], bf[2];

    // prologue: buf0 {A k0 (2 halves), B k0}, buf1 {B k1}
    STGA(0, 0, 0); STGA(0, 1, 0); STGB(0, 0); STGB(1, 1);
    asm volatile("s_waitcnt vmcnt(1)" ::: "memory");   // buf0 landed, B1 in flight
    SCHED(); BAR(); SCHED();

    for (int it = 0; it < nit; ++it) {
        const bool s = (it + 1 < nit);
        const int k1 = 2 * it + 1, k2 = 2 * it + 2, k3 = 2 * it + 3;

        // ph1: read af(buf0,mq0)+bf(buf0); stage A-buf1 (k1) both halves
#pragma unroll
        for (int t_ = 0; t_ < 4; ++t_) af[t_] = LDA32(0, 0, t_);
#pragma unroll
        for (int n = 0; n < 2; ++n) bf[n] = LDB32(0, n);
        STGA(1, 0, k1); STGA(1, 1, k1);
        SCHED(); BAR(); SCHED();
        __builtin_amdgcn_s_setprio(1); MM32(0); __builtin_amdgcn_s_setprio(0);
        SCHED(); BAR(); SCHED();

        // ph2: read af(buf0,mq1); stage B-buf0 (k2); wait -> buf1 ready
#pragma unroll
        for (int t_ = 0; t_ < 4; ++t_) af[t_] = LDA32(0, 1, t_);
        if (s) STGB(0, k2);
        SCHED(); BAR(); SCHED();
        __builtin_amdgcn_s_setprio(1); MM32(1); __builtin_amdgcn_s_setprio(0);
        if (s) asm volatile("s_waitcnt vmcnt(1)" ::: "memory");
        else   asm volatile("s_waitcnt vmcnt(0)" ::: "memory");
        SCHED(); BAR(); SCHED();

        // ph3: read af(buf1,mq0)+bf(buf1); stage A-buf0 (k2) both halves
#pragma unroll
        for (int t_ = 0; t_ < 4; ++t_) af[t_] = LDA32(1, 0, t_);
#pragma unroll
        for (int n = 0; n < 2; ++n) bf[n] = LDB32(1, n);
        if (s) { STGA(0, 0, k2); STGA(0, 1, k2); }
        SCHED(); BAR(); SCHED();
        __builtin_amdgcn_s_setprio(1); MM32(0); __builtin_amdgcn_s_setprio(0);
        SCHED(); BAR(); SCHED();

        // ph4: read af(buf1,mq1); stage B-buf1 (k3); wait -> buf0 ready
#pragma unroll
        for (int t_ = 0; t_ < 4; ++t_) af[t_] = LDA32(1, 1, t_);
        if (s) STGB(1, k3);
        SCHED(); BAR(); SCHED();
        __builtin_amdgcn_s_setprio(1); MM32(1); __builtin_amdgcn_s_setprio(0);
        if (s) asm volatile("s_waitcnt vmcnt(1)" ::: "memory");
        SCHED(); BAR(); SCHED();
    }

    // epilogue: bias/scale in-register, u16 LDS transpose, 16B stores.
    // C/D frag: col = l15 (+nt*16), row = quad*4+reg (+mt*16).
    int colb_w = colb + wn * 32;
    int rowb_w = rowb + wm * 128;
    u16* ebw = smem + wave * (16 * ES2);
    int lr = lane >> 2;
    int ec = (lane & 3) * 8;
    float bcol[2];
    if (MODE == 0) {
#pragma unroll
        for (int nt = 0; nt < 2; ++nt)
            bcol[nt] = bi_p[colb_w + nt * 16 + l15];
    }
#pragma unroll
    for (int mt = 0; mt < 8; ++mt) {
#pragma unroll
        for (int nt = 0; nt < 2; ++nt) {
            f32x4 a = acc[mt][nt];
#pragma unroll
            for (int reg = 0; reg < 4; ++reg) {
                float fv = a[reg];
                if (MODE == 0) fv += bcol[nt];
                else fv *= SCALE;
                ebw[(quad * 4 + reg) * ES2 + nt * 16 + l15] = f2bf(fv);
            }
        }
        // wave-private region: in-wave DS ordering, no barrier needed
        bf16x8 vv = *(const bf16x8*)&ebw[lr * ES2 + ec];
        size_t cidx = (size_t)cb * bsC + (size_t)(rowb_w + mt * 16 + lr) * rsC
                      + colb_w + ec;
        *(bf16x8*)&((u16*)out)[cidx] = vv;
    }
}

// ------------------------------------------------------------- MFMA GEMM
// Proven 256x256 BK=64 single-tile template (R4 NT=1 path).
// MODE 1: v, bf16 out +bias[row]
// MODE 3: pv (A=S0/S1, out=O0/O1), bf16 out
// MODE 4: proj (B=O0/O1), f32 out +bias[row]+resid

#define MM(mq, nq) do { \
    _Pragma("unroll") \
    for (int t_ = 0; t_ < 4; ++t_) { \
        _Pragma("unroll") \
        for (int n_ = 0; n_ < 2; ++n_) { \
            _Pragma("unroll") \
            for (int ks_ = 0; ks_ < 2; ++ks_) \
                acc[(mq)*4 + t_][(nq)*2 + n_] = \
                    __builtin_amdgcn_mfma_f32_16x16x32_bf16( \
                        af[t_][ks_], bf[(nq)*2 + n_][ks_], \
                        acc[(mq)*4 + t_][(nq)*2 + n_], 0, 0, 0); \
        } \
    } \
} while (0)

template <int MODE>
__global__ __launch_bounds__(512, 2) void gemm_kernel(
        const u16* __restrict__ A, const u16* __restrict__ A2,
        const u16* __restrict__ B, const u16* __restrict__ B2,
        void* __restrict__ Cv, void* __restrict__ Cv2,
        const float* __restrict__ bias, const float* __restrict__ xres,
        int K, int rsA, int rsB, int rsC,
        long long bsA, long long bsB, long long bsC,
        int nx, int ny) {
    int flat = blockIdx.x;
    int t = (flat & 7) * 32 + (flat >> 3);     // nwg = 256
    int bx = t % nx, by = (t / nx) % ny, bz = t / (nx * ny);
    int b = bz;
    const u16 *gA, *gB;
    void* out = Cv;
    if (MODE == 3) {
        gA = ((b >= 16) ? A2 : A) + (size_t)(b & 15) * bsA + (size_t)by * 256 * rsA;
        gB = B + (size_t)b * bsB + (size_t)bx * 256 * rsB;
        out = (b >= 16) ? Cv2 : Cv;
    } else if (MODE == 4) {
        gA = A + (size_t)by * 256 * rsA;
        gB = ((b >= 16) ? B2 : B) + (size_t)(b & 15) * bsB + (size_t)bx * 256 * rsB;
    } else {  // MODE 1
        gA = A + (size_t)by * 256 * rsA;
        gB = B + (size_t)b * bsB + (size_t)bx * 256 * rsB;
    }
    int cb = (MODE == 3) ? (b & 15) : b;

    // 128 KB: [0,16K)=A0 [16K,32K)=B0 [32K,48K)=A1 [48K,64K)=B1  (u16 idx)
    __shared__ __align__(16) u16 smem[65536];

    int tid = threadIdx.x;
    int lane = tid & 63, wave = tid >> 6;
    int wm = wave >> 2, wn = wave & 3;
    int quad = lane >> 4, l15 = lane & 15, l7 = lane & 7;
    int srow = tid >> 3;
    int lg = (tid & 7) ^ (srow & 7);

    const int nk = K >> 6;
    const int nit = nk >> 1;

    auto STG = [&](const u16* g, int rs, int buf, int isB, int hh, int kt) {
        const u16* src = g + (size_t)(hh * 128 + srow) * rs + (size_t)kt * 64 + lg * 8;
        u16* dst = &smem[buf * 32768 + isB * 16384 + (hh * 128 + srow) * 64 + (tid & 7) * 8];
        gl_lds16(src, dst);
        gl_lds16(src + (size_t)64 * rs, dst + 4096);
    };
    auto LDA = [&](int buf, int mq, int t_, int ks) -> bf16x8 {
        return *(const bf16x8*)&smem[buf * 32768 +
            (wm * 128 + mq * 64 + t_ * 16 + l15) * 64 + (((ks * 4 + quad) ^ l7) << 3)];
    };
    auto LDB = [&](int buf, int nt, int ks) -> bf16x8 {
        return *(const bf16x8*)&smem[buf * 32768 + 16384 +
            (wn * 64 + nt * 16 + l15) * 64 + (((ks * 4 + quad) ^ l7) << 3)];
    };

    f32x4 acc[8][4];
#pragma unroll
    for (int mt = 0; mt < 8; ++mt)
#pragma unroll
        for (int nt = 0; nt < 4; ++nt)
            acc[mt][nt] = (f32x4){0.f, 0.f, 0.f, 0.f};
    bf16x8 af[4][2], bf[4][2];

    // cold prologue: buf0 full (tile k0), buf1 B-halves (k1)
    STG(gB, rsB, 0, 1, 0, 0); STG(gB, rsB, 0, 1, 1, 0);
    STG(gA, rsA, 0, 0, 0, 0); STG(gA, rsA, 0, 0, 1, 0);
    STG(gB, rsB, 1, 1, 0, 1); STG(gB, rsB, 1, 1, 1, 1);
    asm volatile("s_waitcnt vmcnt(4)" ::: "memory");
    SCHED(); BAR(); SCHED();

    for (int it = 0; it < nit; ++it) {
        const bool s = (it + 1 < nit);
        const int k1 = 2 * it + 1, k2 = 2 * it + 2, k3 = 2 * it + 3;

        // phase 1
#pragma unroll
        for (int t_ = 0; t_ < 4; ++t_)
#pragma unroll
            for (int ks = 0; ks < 2; ++ks) af[t_][ks] = LDA(0, 0, t_, ks);
#pragma unroll
        for (int n = 0; n < 2; ++n)
#pragma unroll
            for (int ks = 0; ks < 2; ++ks) bf[n][ks] = LDB(0, n, ks);
        STG(gA, rsA, 1, 0, 0, k1);
        SCHED(); BAR(); SCHED();
        __builtin_amdgcn_s_setprio(1); MM(0, 0); __builtin_amdgcn_s_setprio(0);
        SCHED(); BAR(); SCHED();

        // phase 2
#pragma unroll
        for (int n = 2; n < 4; ++n)
#pragma unroll
            for (int ks = 0; ks < 2; ++ks) bf[n][ks] = LDB(0, n, ks);
        STG(gA, rsA, 1, 0, 1, k1);
        SCHED(); BAR(); SCHED();
        __builtin_amdgcn_s_setprio(1); MM(0, 1); __builtin_amdgcn_s_setprio(0);
        SCHED(); BAR(); SCHED();

        // phase 3
#pragma unroll
        for (int t_ = 0; t_ < 4; ++t_)
#pragma unroll
            for (int ks = 0; ks < 2; ++ks) af[t_][ks] = LDA(0, 1, t_, ks);
        if (s) STG(gB, rsB, 0, 1, 0, k2);
        SCHED(); BAR(); SCHED();
        __builtin_amdgcn_s_setprio(1); MM(1, 1); __builtin_amdgcn_s_setprio(0);
        SCHED(); BAR(); SCHED();

        // phase 4
        if (s) STG(gB, rsB, 0, 1, 1, k2);
        SCHED(); BAR(); SCHED();
        __builtin_amdgcn_s_setprio(1); MM(1, 0); __builtin_amdgcn_s_setprio(0);
        if (s) asm volatile("s_waitcnt vmcnt(4)" ::: "memory");
        else   asm volatile("s_waitcnt vmcnt(0)" ::: "memory");
        SCHED(); BAR(); SCHED();

        // phase 5
#pragma unroll
        for (int t_ = 0; t_ < 4; ++t_)
#pragma unroll
            for (int ks = 0; ks < 2; ++ks) af[t_][ks] = LDA(1, 0, t_, ks);
#pragma unroll
        for (int n = 0; n < 2; ++n)
#pragma unroll
            for (int ks = 0; ks < 2; ++ks) bf[n][ks] = LDB(1, n, ks);
        if (s) STG(gA, rsA, 0, 0, 0, k2);
        SCHED(); BAR(); SCHED();
        __builtin_amdgcn_s_setprio(1); MM(0, 0); __builtin_amdgcn_s_setprio(0);
        SCHED(); BAR(); SCHED();

        // phase 6
#pragma unroll
        for (int n = 2; n < 4; ++n)
#pragma unroll
            for (int ks = 0; ks < 2; ++ks) bf[n][ks] = LDB(1, n, ks);
        if (s) STG(gA, rsA, 0, 0, 1, k2);
        SCHED(); BAR(); SCHED();
        __builtin_amdgcn_s_setprio(1); MM(0, 1); __builtin_amdgcn_s_setprio(0);
        SCHED(); BAR(); SCHED();

        // phase 7
#pragma unroll
        for (int t_ = 0; t_ < 4; ++t_)
#pragma unroll
            for (int ks = 0; ks < 2; ++ks) af[t_][ks] = LDA(1, 1, t_, ks);
        if (s) STG(gB, rsB, 1, 1, 0, k3);
        SCHED(); BAR(); SCHED();
        __builtin_amdgcn_s_setprio(1); MM(1, 1); __builtin_amdgcn_s_setprio(0);
        SCHED(); BAR(); SCHED();

        // phase 8
        if (s) STG(gB, rsB, 1, 1, 1, k3);
        SCHED(); BAR(); SCHED();
        __builtin_amdgcn_s_setprio(1); MM(1, 0); __builtin_amdgcn_s_setprio(0);
        if (s) asm volatile("s_waitcnt vmcnt(4)" ::: "memory");
        SCHED(); BAR(); SCHED();
    }

    // epilogue (scratch in buf1-A region [32768,49152))
    int colb = bx * 256 + wn * 64;
    int rowb = by * 256 + wm * 128;

    if (MODE == 4) {
        float* ebw = (float*)(smem + 32768) + wave * (16 * ESTRIDE);
        int er = lane >> 4;
        int ec4 = (lane & 15) * 4;
#pragma unroll
        for (int mt = 0; mt < 8; ++mt) {
#pragma unroll
            for (int nt = 0; nt < 4; ++nt) {
                f32x4 a = acc[mt][nt];
#pragma unroll
                for (int reg = 0; reg < 4; ++reg)
                    ebw[(quad * 4 + reg) * ESTRIDE + nt * 16 + l15] = a[reg];
            }
#pragma unroll
            for (int j = 0; j < 4; ++j) {
                int lr = er + 4 * j;
                f32x2 v0 = *(f32x2*)&ebw[lr * ESTRIDE + ec4];
                f32x2 v1 = *(f32x2*)&ebw[lr * ESTRIDE + ec4 + 2];
                int gr = rowb + mt * 16 + lr;
                int gc = colb + ec4;
                size_t cidx = (size_t)cb * bsC + (size_t)gr * rsC + gc;
                float bi = bias[gr];
                float4 xr = *(const float4*)&xres[cidx];
                float4 st = make_float4(v0.x + bi + xr.x, v0.y + bi + xr.y,
                                        v1.x + bi + xr.z, v1.y + bi + xr.w);
                *(float4*)&((float*)out)[cidx] = st;
            }
        }
    } else {
        u16* ebw = (smem + 32768) + wave * (16 * ESTRU);
        int er = lane >> 3;
        int ec = (lane & 7) * 8;
#pragma unroll
        for (int mt = 0; mt < 8; ++mt) {
            float4 brow = make_float4(0.f, 0.f, 0.f, 0.f);
            if (MODE == 1)
                brow = *(const float4*)&bias[rowb + mt * 16 + quad * 4];
#pragma unroll
            for (int nt = 0; nt < 4; ++nt) {
                f32x4 a = acc[mt][nt];
#pragma unroll
                for (int reg = 0; reg < 4; ++reg) {
                    float fv = a[reg];
                    if (MODE == 1) fv += ((const float*)&brow)[reg];
                    ebw[(quad * 4 + reg) * ESTRU + nt * 16 + l15] = f2bf(fv);
                }
            }
#pragma unroll
            for (int j = 0; j < 2; ++j) {
                int lr = er + 8 * j;
                bf16x8 vv = *(const bf16x8*)&ebw[lr * ESTRU + ec];
                int gr = rowb + mt * 16 + lr;
                size_t cidx = (size_t)cb * bsC + (size_t)gr * rsC + colb + ec;
                *(bf16x8*)&((u16*)out)[cidx] = vv;
            }
        }
    }
}

// ------------------------------------------------------------- Softmax
// bf16 S row (1024) -> bf16 P in place. wave-per-row, 4 rows/block.
__global__ __launch_bounds__(256) void softmax_kernel(
        u16* __restrict__ S0, u16* __restrict__ S1) {
    int row = blockIdx.x * 4 + (threadIdx.x >> 6);
    int lane = threadIdx.x & 63;
    u16* p = ((row & 16384) ? S1 : S0) + (size_t)(row & 16383) * N_PIX + lane * 16;
    bf16x8 u0 = *(const bf16x8*)p;
    bf16x8 u1 = *(const bf16x8*)(p + 8);
    float f[16];
#pragma unroll
    for (int i = 0; i < 8; ++i) {
        f[i] = bf2f((u16)u0[i]);
        f[8 + i] = bf2f((u16)u1[i]);
    }
    float m = f[0];
#pragma unroll
    for (int i = 1; i < 16; ++i) m = fmaxf(m, f[i]);
#pragma unroll
    for (int off = 1; off < 64; off <<= 1) m = fmaxf(m, __shfl_xor(m, off));
    float s = 0.f;
#pragma unroll
    for (int i = 0; i < 16; ++i) { f[i] = __expf(f[i] - m); s += f[i]; }
#pragma unroll
    for (int off = 1; off < 64; off <<= 1) s += __shfl_xor(s, off);
    float inv = 1.0f / s;
    bf16x8 s0, s1;
#pragma unroll
    for (int i = 0; i < 8; ++i) {
        s0[i] = (short)f2bf(f[i] * inv);
        s1[i] = (short)f2bf(f[8 + i] * inv);
    }
    *(bf16x8*)p = s0;
    *(bf16x8*)(p + 8) = s1;
}

extern "C" void kernel_launch(void* const* d_in, const int* in_sizes, int n_in,
                              void* d_out, int out_size, void* d_ws, size_t ws_size,
                              hipStream_t stream) {
    const float* x    = (const float*)d_in[0];
    const float* gn_w = (const float*)d_in[1];
    const float* gn_b = (const float*)d_in[2];
    const float* wq   = (const float*)d_in[3];
    const float* bq   = (const float*)d_in[4];
    const float* wk   = (const float*)d_in[5];
    const float* bk   = (const float*)d_in[6];
    const float* wv   = (const float*)d_in[7];
    const float* bv   = (const float*)d_in[8];
    const float* wp   = (const float*)d_in[9];
    const float* bp   = (const float*)d_in[10];
    float* y = (float*)d_out;

    const size_t BCN = (size_t)BATCH * C_DIM * N_PIX;
    char* w = (char*)d_ws;
    u16* h  = (u16*)(w);                       // reused as S0
    u16* q  = (u16*)(w + 2 * BCN);             // reused as O0
    u16* k  = (u16*)(w + 4 * BCN);             // reused as O1
    u16* v  = (u16*)(w + 6 * BCN);
    u16* Or = (u16*)(w + 8 * BCN);             // reused as S1
    u16* wb = (u16*)(w + 10 * BCN);            // 2 MB bf16 weights
    u16* wvb = wb + 524288, *wpb = wb + 786432;
    float* stats = (float*)(w + 10 * BCN + 2 * 1024 * 1024);   // 8 KB
    u16* S0 = h;
    u16* S1 = Or;
    u16* O0 = q;
    u16* O1 = k;

    const long long BS = 524288;               // per-batch elems
    const long long SB = 1048576;              // per-batch S elems

    prep_kernel<<<2048, 256, 0, stream>>>(wq, wk, wv, wp, wb, x, stats);
    gnt_kernel<<<512, 256, 0, stream>>>(x, gn_w, gn_b, stats, h);

    // q,k[n][o] = h[n][c]*w[o][c] + b[o]   M=1024 N=512 K=512, 1024 tiles
    gemm32_kernel<0><<<1024, 512, 0, stream>>>(
        h, wb, q, k, bq, bk, 512, 512, 512, 512, BS, 0, BS);
    // v[c][n] = wv[c][c']*h[n][c'] + bv[c]  M=512 N=1024 K=512
    gemm_kernel<1><<<256, 512, 0, stream>>>(
        wvb, nullptr, h, nullptr, v, nullptr, bv, nullptr,
        512, 512, 512, 1024, 0, BS, BS, 4, 2);

    // S[i][j] = SCALE * q[i][o]*k[j][o]  M=N=1024 K=512, 1024 tiles
    gemm32_kernel<2><<<1024, 512, 0, stream>>>(
        q, k, S0, S1, nullptr, nullptr, 512, 512, 512, 1024, BS, BS, SB);
    softmax_kernel<<<8192, 256, 0, stream>>>(S0, S1);
    // O[i][c] = P[i][j]*v[c][j]  M=1024 N=512 K=1024
    gemm_kernel<3><<<256, 512, 0, stream>>>(
        S0, S1, v, nullptr, O0, O1, nullptr, nullptr,
        1024, 1024, 1024, 512, SB, BS, BS, 2, 4);

    // y[o][n] = x + bp[o] + wp[o][c]*O[n][c]  M=512 N=1024 K=512
    gemm_kernel<4><<<256, 512, 0, stream>>>(
        wpb, nullptr, O0, O1, y, nullptr, bp, x,
        512, 512, 512, 1024, 0, BS, BS, 4, 2);
}